// Round 5
// baseline (384.491 us; speedup 1.0000x reference)
//
#include <hip/hip_runtime.h>
#include <stdint.h>

#define NB 16384       // batch rows
#define DI 2048        // d_in
#define DO 2048        // d_out
#define KTOP 256
#define LIST_CAP 384
#define MT (NB / 256)  // 256-row tiles for partial sums (64)

typedef __attribute__((ext_vector_type(4))) float f32x4;
typedef __attribute__((ext_vector_type(8))) short s16x8;
typedef __attribute__((ext_vector_type(8))) unsigned short u16x8;

// OWA weights: w(rank) = (1 - 0.9*rank/255)/140.8
#define OWA_C0 7.10227273e-3f
#define OWA_C1 2.50668449e-5f

__device__ __forceinline__ ushort f2bf(float f) {
  uint32_t u = __float_as_uint(f);
  uint32_t r = (u + 0x7FFFu + ((u >> 16) & 1u)) >> 16;  // RNE
  return (ushort)r;
}

__device__ __forceinline__ void gld_lds16(const void* g, void* l) {
  __builtin_amdgcn_global_load_lds((__attribute__((address_space(1))) void*)g,
                                   (__attribute__((address_space(3))) void*)l,
                                   16, 0, 0);
}

// ---------------------------------------------------------------------------
// K0: convert W (fp32 [DO][DI]) -> bf16
__global__ __launch_bounds__(256) void k_cvt(const float* __restrict__ W,
                                             ushort* __restrict__ Wb) {
  size_t i = ((size_t)blockIdx.x * 256 + threadIdx.x) * 8;
  float4 a = *(const float4*)(W + i);
  float4 b = *(const float4*)(W + i + 4);
  u16x8 o;
  o[0] = f2bf(a.x); o[1] = f2bf(a.y); o[2] = f2bf(a.z); o[3] = f2bf(a.w);
  o[4] = f2bf(b.x); o[5] = f2bf(b.y); o[6] = f2bf(b.z); o[7] = f2bf(b.w);
  *(u16x8*)(Wb + i) = o;
}

// ---------------------------------------------------------------------------
// K1: per-row mu + top-k(256) OWA -> A (bf16). One block (256 thr) per row.
__global__ __launch_bounds__(256) void k_topk(
    const float* __restrict__ x, const float* __restrict__ center,
    const float* __restrict__ sharp, float* __restrict__ mu_out,
    ushort* __restrict__ A) {
  __shared__ __align__(16) float w_lds[DI];   // OWA weight per column (0 if not selected)
  __shared__ uint32_t histR[8 * 256];         // 8-way replicated histogram
  __shared__ uint64_t list[LIST_CAP];         // candidate keys (bits<<32 | (DI-1-idx))
  __shared__ uint32_t scal[4];

  const int t = threadIdx.x;
  const int lane = t & 63;
  const int wv = t >> 6;
  const int row = blockIdx.x;
  const int base = t * 8;

  const float* xr = x + (size_t)row * DI + base;
  float4 xa = *(const float4*)(xr);
  float4 xb = *(const float4*)(xr + 4);
  float4 ca = *(const float4*)(center + base);
  float4 cb = *(const float4*)(center + base + 4);
  float4 sa = *(const float4*)(sharp + base);
  float4 sb = *(const float4*)(sharp + base + 4);

  float xv[8] = {xa.x, xa.y, xa.z, xa.w, xb.x, xb.y, xb.z, xb.w};
  float cv[8] = {ca.x, ca.y, ca.z, ca.w, cb.x, cb.y, cb.z, cb.w};
  float sv[8] = {sa.x, sa.y, sa.z, sa.w, sb.x, sb.y, sb.z, sb.w};
  float muv[8];
  uint32_t bits[8];
#pragma unroll
  for (int e = 0; e < 8; ++e) {
    float s = sv[e] * (xv[e] - cv[e]);
    float m = 1.0f / (1.0f + __expf(-s));
    muv[e] = m;
    bits[e] = __float_as_uint(m);  // mu>0 -> bit pattern is order-preserving
  }
  if (mu_out) {
    float4 m0; m0.x = muv[0]; m0.y = muv[1]; m0.z = muv[2]; m0.w = muv[3];
    float4 m1; m1.x = muv[4]; m1.y = muv[5]; m1.z = muv[6]; m1.w = muv[7];
    *(float4*)(mu_out + (size_t)row * DI + base) = m0;
    *(float4*)(mu_out + (size_t)row * DI + base + 4) = m1;
  }
  // zero weight array (scattered into much later; barriers in between)
  float4 z4; z4.x = z4.y = z4.z = z4.w = 0.f;
  *(float4*)(w_lds + base) = z4;
  *(float4*)(w_lds + base + 4) = z4;

  // ---- 4-pass byte radix select for the 256th-largest bit pattern ----
  uint32_t maskHi = 0, pfx = 0;
  uint32_t k_rem = KTOP;
  const uint32_t rep = (uint32_t)(t & 7) * 256u;
#pragma unroll 1
  for (int pass = 0; pass < 4; ++pass) {
    const int shift = 24 - pass * 8;
#pragma unroll
    for (int i = 0; i < 8; ++i) histR[t + 256 * i] = 0;
    __syncthreads();
#pragma unroll
    for (int e = 0; e < 8; ++e) {
      uint32_t bb = bits[e];
      if ((bb & maskHi) == pfx)
        atomicAdd(&histR[rep + ((bb >> shift) & 255u)], 1u);
    }
    __syncthreads();
    if (wv == 0) {  // single-wave suffix scan over 256 bins, no barriers
      uint32_t c0 = 0, c1 = 0, c2 = 0, c3 = 0;
#pragma unroll
      for (int r = 0; r < 8; ++r) {
        const uint32_t* h = &histR[r * 256 + lane * 4];
        c0 += h[0]; c1 += h[1]; c2 += h[2]; c3 += h[3];
      }
      uint32_t s3 = c3, s2 = c2 + s3, s1 = c1 + s2, s0 = c0 + s1;
      uint32_t Tl = s0, suf = s0;
#pragma unroll
      for (int off = 1; off < 64; off <<= 1) {
        uint32_t vsh = __shfl_down(suf, off);
        if (lane + off < 64) suf += vsh;
      }
      uint32_t above = suf - Tl;  // total of lanes > lane
      uint32_t SS[4] = {s0 + above, s1 + above, s2 + above, s3 + above};
      uint32_t cc[4] = {c0, c1, c2, c3};
#pragma unroll
      for (int j = 0; j < 4; ++j) {
        if (SS[j] >= k_rem && (SS[j] - cc[j]) < k_rem) {
          scal[0] = (uint32_t)(lane * 4 + j);
          scal[1] = SS[j] - cc[j];  // count strictly greater (this level)
        }
      }
    }
    __syncthreads();
    uint32_t v = scal[0], g = scal[1];
    pfx |= (v << shift);
    maskHi |= (0xFFu << shift);
    k_rem -= g;
  }
  const uint32_t tb = pfx;  // exact bit pattern of the 256th largest

  // ---- compact candidates (bits >= tb) ----
  if (t == 0) scal[2] = 0;
  __syncthreads();
#pragma unroll
  for (int e = 0; e < 8; ++e) {
    if (bits[e] >= tb) {
      uint32_t pos = atomicAdd(&scal[2], 1u);
      if (pos < LIST_CAP)
        list[pos] = ((uint64_t)bits[e] << 32) |
                    (uint64_t)(uint32_t)(DI - 1 - (base + e));
    }
  }
  __syncthreads();
  int L = (int)scal[2];
  if (L > LIST_CAP) L = LIST_CAP;

  // ---- exact ranks among candidates (key includes stable index tiebreak) ----
  for (int sIdx = t; sIdx < L; sIdx += 256) {
    uint64_t key = list[sIdx];
    int rank = 0;
#pragma unroll 4
    for (int j = 0; j < L; ++j) rank += (int)(list[j] > key);
    if (rank < KTOP) {
      int idx = DI - 1 - (int)((uint32_t)key & 0xFFFFFFFFu);
      w_lds[idx] = OWA_C0 - OWA_C1 * (float)rank;
    }
  }
  __syncthreads();

  // ---- emit A[b,i] = w * mu * x as bf16 (coalesced 16B stores) ----
  u16x8 ov;
#pragma unroll
  for (int e = 0; e < 8; ++e) ov[e] = f2bf(w_lds[base + e] * muv[e] * xv[e]);
  *(u16x8*)(A + (size_t)row * DI + base) = ov;
}

// ---------------------------------------------------------------------------
// K2: 256x256x64 8-phase pipelined GEMM (T2+T3+T4+T5), m201-faithful.
//
// KEY INVARIANT (R5): phase q touches ONLY A rows [64q, 64q+64) because wave
// wm owns scattered rows {64q + wm*32 + [0,32)}, not a contiguous 128-row
// half. So A-h0 is consumed only in phases 0-1, A-h1 only in phases 2-3:
//   stage: (T,0): A(T+1)h0  (T,1): A(T+1)h1  (T,2): B(T+2)h0  (T,3): B(T+2)h1
//   waits: (T,1) vmcnt(8)  -> A(T)h1 landed before (T,2) reads it
//          (T,3) vmcnt(6)  -> A(T+1)h0 + B(T+1) landed before (T+1,0)
//   (in-order VMEM retirement makes both exact; 3-4 half-tiles in flight,
//    never vmcnt(0) in steady state). Epilogue: T=30 vmcnt(1), (31,1) vmcnt(0).
// Chunk-XOR swizzle (R2, 0-conflict): LDS[row][c] = global[row][c ^ (row&7)].
#define HALFS 8192  // ushorts per half-slot (128 rows x 64 cols)

#define STAGE_A(U, h)                                             \
  do {                                                            \
    ushort* sl = lA + (((((U) & 1) << 1) + (h)) * HALFS);         \
    gld_lds16(pA[h][0] + (size_t)(U) * 64, sl + d0);              \
    gld_lds16(pA[h][1] + (size_t)(U) * 64, sl + d1);              \
  } while (0)

#define STAGE_B(U, h)                                             \
  do {                                                            \
    ushort* sl = lB + (((((U) & 1) << 1) + (h)) * HALFS);         \
    gld_lds16(pB[h][0] + (size_t)(U) * 64, sl + d0);              \
    gld_lds16(pB[h][1] + (size_t)(U) * 64, sl + d1);              \
  } while (0)

#define MFMA_PHASE(q, A00, A01, A10, A11)                                      \
  do {                                                                         \
    __builtin_amdgcn_s_setprio(1);                                             \
    _Pragma("unroll") for (int ni = 0; ni < 4; ++ni) {                         \
      acc[2 * (q)][ni] = __builtin_amdgcn_mfma_f32_16x16x32_bf16(              \
          A00, breg[ni][0], acc[2 * (q)][ni], 0, 0, 0);                        \
      acc[2 * (q)][ni] = __builtin_amdgcn_mfma_f32_16x16x32_bf16(              \
          A01, breg[ni][1], acc[2 * (q)][ni], 0, 0, 0);                        \
      acc[2 * (q) + 1][ni] = __builtin_amdgcn_mfma_f32_16x16x32_bf16(          \
          A10, breg[ni][0], acc[2 * (q) + 1][ni], 0, 0, 0);                    \
      acc[2 * (q) + 1][ni] = __builtin_amdgcn_mfma_f32_16x16x32_bf16(          \
          A11, breg[ni][1], acc[2 * (q) + 1][ni], 0, 0, 0);                    \
    }                                                                          \
    __builtin_amdgcn_s_setprio(0);                                             \
  } while (0)

// phase q: A rows (in half q>>1) = (q&1)*64 + wm*32 + {0,16} + fr
#define PHASE(q, STAGE_STMT, TAIL_STMT)                                        \
  do {                                                                         \
    const ushort* sA_ = lApar + ((q) >> 1) * HALFS;                            \
    const int ar_ = (((q) & 1) * 64 + wm32) * 64 + aoff;                       \
    s16x8 a00 = *(const s16x8*)(sA_ + ar_ + c0);                               \
    s16x8 a01 = *(const s16x8*)(sA_ + ar_ + c1);                               \
    s16x8 a10 = *(const s16x8*)(sA_ + ar_ + 16 * 64 + c0);                     \
    s16x8 a11 = *(const s16x8*)(sA_ + ar_ + 16 * 64 + c1);                     \
    STAGE_STMT;                                                                \
    __builtin_amdgcn_s_barrier();                                              \
    asm volatile("s_waitcnt lgkmcnt(0)" ::: "memory");                         \
    __builtin_amdgcn_sched_barrier(0);                                         \
    MFMA_PHASE(q, a00, a01, a10, a11);                                         \
    TAIL_STMT;                                                                 \
    __builtin_amdgcn_s_barrier();                                              \
  } while (0)

__global__ __launch_bounds__(512, 2) void k_gemm(
    const ushort* __restrict__ A, const ushort* __restrict__ Wb,
    const float* __restrict__ bias, float* __restrict__ outp,
    float* __restrict__ psum, float* __restrict__ psumsq) {
  __shared__ __align__(16) ushort lA[4 * HALFS];
  __shared__ __align__(16) ushort lB[4 * HALFS];

  const int t = threadIdx.x;
  const int lane = t & 63;
  const int wv = t >> 6;
  const int wm = wv >> 2;   // 0..1: row-group parity (rows 64q + wm*32 + [0,32))
  const int wn = wv & 3;    // 0..3: 64-col strip of the N tile
  const int wm32 = wm * 32;
  const int fr = lane & 15;
  const int kg = lane >> 4;
  const int s = fr & 7;

  // XCD-aware bijective swizzle (512 blocks, 512 % 8 == 0)
  int bid = blockIdx.x;
  int orig = (bid & 7) * 64 + (bid >> 3);
  const int nb = orig & 7;
  const int mb = orig >> 3;
  const int m0 = mb * 256;
  const int n0 = nb * 256;

  // staging: thread t covers in-slot row (load0) t>>3, (load1) 64 + t>>3;
  // chunk t&7 holds global chunk (t&7)^(row&7)
  const int srow0 = t >> 3;
  const int scol = ((t & 7) ^ (srow0 & 7)) * 8;
  const ushort* pA[2][2];
  const ushort* pB[2][2];
#pragma unroll
  for (int h = 0; h < 2; ++h) {
#pragma unroll
    for (int i = 0; i < 2; ++i) {
      pA[h][i] = A + (size_t)(m0 + h * 128 + i * 64 + srow0) * DI + scol;
      pB[h][i] = Wb + (size_t)(n0 + h * 128 + i * 64 + srow0) * DI + scol;
    }
  }
  const int d0 = t * 8;          // LDS dst (ushorts) for load 0
  const int d1 = (512 + t) * 8;  // load 1

  f32x4 acc[8][4];
#pragma unroll
  for (int i = 0; i < 8; ++i)
#pragma unroll
    for (int j = 0; j < 4; ++j) acc[i][j] = (f32x4){0.f, 0.f, 0.f, 0.f};

  // prologue: B(0), A(0), B(1) = 12 loads; vmcnt(6) forces B(0)+A(0)h0
  STAGE_B(0, 0); STAGE_B(0, 1);
  STAGE_A(0, 0); STAGE_A(0, 1);
  STAGE_B(1, 0); STAGE_B(1, 1);
  asm volatile("s_waitcnt vmcnt(6)" ::: "memory");
  __builtin_amdgcn_s_barrier();

  // fragment read offsets (ushorts)
  const int aoff = fr * 64;
  const int c0 = (kg ^ s) * 8;
  const int c1 = ((4 + kg) ^ s) * 8;
  const int boff = ((wn & 1) * 64 + fr) * 64;

  s16x8 breg[4][2];

#pragma unroll 1
  for (int T = 0; T < 32; ++T) {
    const ushort* lApar = lA + ((T & 1) << 1) * HALFS;
    const ushort* sBp = lB + (((T & 1) << 1) + (wn >> 1)) * HALFS;

#pragma unroll
    for (int ni = 0; ni < 4; ++ni) {
      breg[ni][0] = *(const s16x8*)(sBp + ni * 1024 + boff + c0);
      breg[ni][1] = *(const s16x8*)(sBp + ni * 1024 + boff + c1);
    }
    PHASE(0, if (T < 31) STAGE_A(T + 1, 0), );
    PHASE(1, if (T < 31) STAGE_A(T + 1, 1),
          if (T < 31) { asm volatile("s_waitcnt vmcnt(8)" ::: "memory"); }
          else { asm volatile("s_waitcnt vmcnt(0)" ::: "memory"); });
    PHASE(2, if (T < 30) STAGE_B(T + 2, 0), );
    PHASE(3, if (T < 30) STAGE_B(T + 2, 1),
          if (T < 30) { asm volatile("s_waitcnt vmcnt(6)" ::: "memory"); }
          else if (T == 30) { asm volatile("s_waitcnt vmcnt(1)" ::: "memory"); });
  }

  // epilogue: bias + relu + store + deterministic column partials
  __syncthreads();
  float* colsum = (float*)lA;     // reuse tile LDS
  float* colsq = colsum + 256;
  if (t < 256) { colsum[t] = 0.f; colsq[t] = 0.f; }
  __syncthreads();
#pragma unroll
  for (int ni = 0; ni < 4; ++ni) {
    const int n = n0 + wn * 64 + ni * 16 + fr;
    const float bv = bias[n];
    float cs = 0.f, cq = 0.f;
#pragma unroll
    for (int mi = 0; mi < 8; ++mi) {
      // acc[mi] -> tile row 64*(mi>>1) + wm*32 + 16*(mi&1) + kg*4 + r
      const int rowb = m0 + 64 * (mi >> 1) + wm32 + 16 * (mi & 1) + kg * 4;
      f32x4 v = acc[mi][ni];
#pragma unroll
      for (int r = 0; r < 4; ++r) {
        float zz = fmaxf(v[r] + bv, 0.f);
        outp[(size_t)(rowb + r) * DO + n] = zz;
        cs += zz;
        cq += zz * zz;
      }
    }
    cs += __shfl_xor(cs, 16); cq += __shfl_xor(cq, 16);
    cs += __shfl_xor(cs, 32); cq += __shfl_xor(cq, 32);
    if (kg == 0) {  // exactly 2 waves (wm=0,1) add per column bin
      atomicAdd(&colsum[wn * 64 + ni * 16 + fr], cs);
      atomicAdd(&colsq[wn * 64 + ni * 16 + fr], cq);
    }
  }
  __syncthreads();
  if (t < 256) {
    psum[(size_t)mb * DO + n0 + t] = colsum[t];
    psumsq[(size_t)mb * DO + n0 + t] = colsq[t];
  }
}

// ---------------------------------------------------------------------------
// K3: finalize BN scale/shift per column
__global__ __launch_bounds__(256) void k_bnfin(
    const float* __restrict__ psum, const float* __restrict__ psumsq,
    const float* __restrict__ gamma, const float* __restrict__ beta,
    float* __restrict__ scaleA, float* __restrict__ shiftA) {
  int n = blockIdx.x * 256 + threadIdx.x;
  float s = 0.f, q = 0.f;
  for (int r = 0; r < MT; ++r) {
    s += psum[(size_t)r * DO + n];
    q += psumsq[(size_t)r * DO + n];
  }
  float mean = s * (1.0f / (float)NB);
  float var = q * (1.0f / (float)NB) - mean * mean;
  var = fmaxf(var, 0.f);
  float rstd = rsqrtf(var + 1e-5f);
  float sc = gamma[n] * rstd;
  scaleA[n] = sc;
  shiftA[n] = beta[n] - mean * sc;
}

// ---------------------------------------------------------------------------
// K4: y = out*scale + shift, in place over the y region
__global__ __launch_bounds__(256) void k_bnapply(float* __restrict__ outp,
                                                 const float* __restrict__ scaleA,
                                                 const float* __restrict__ shiftA) {
  size_t i = ((size_t)blockIdx.x * 256 + threadIdx.x) * 4;
  int n = (int)(i & (DO - 1));
  float4 v = *(float4*)(outp + i);
  float4 sc = *(const float4*)(scaleA + n);
  float4 sh = *(const float4*)(shiftA + n);
  v.x = v.x * sc.x + sh.x;
  v.y = v.y * sc.y + sh.y;
  v.z = v.z * sc.z + sh.z;
  v.w = v.w * sc.w + sh.w;
  *(float4*)(outp + i) = v;
}

// ---------------------------------------------------------------------------
// K5 (small-ws fallback): recompute mu into the mu region
__global__ __launch_bounds__(256) void k_mu(const float* __restrict__ x,
                                            const float* __restrict__ center,
                                            const float* __restrict__ sharp,
                                            float* __restrict__ mu_out) {
  const int t = threadIdx.x;
  const int row = blockIdx.x;
  const int base = t * 8;
  const float* xr = x + (size_t)row * DI + base;
  float4 xa = *(const float4*)(xr);
  float4 xb = *(const float4*)(xr + 4);
  float4 ca = *(const float4*)(center + base);
  float4 cb = *(const float4*)(center + base + 4);
  float4 sa = *(const float4*)(sharp + base);
  float4 sb = *(const float4*)(sharp + base + 4);
  float xv[8] = {xa.x, xa.y, xa.z, xa.w, xb.x, xb.y, xb.z, xb.w};
  float cv[8] = {ca.x, ca.y, ca.z, ca.w, cb.x, cb.y, cb.z, cb.w};
  float sv[8] = {sa.x, sa.y, sa.z, sa.w, sb.x, sb.y, sb.z, sb.w};
  float mu[8];
#pragma unroll
  for (int e = 0; e < 8; ++e) {
    float s = sv[e] * (xv[e] - cv[e]);
    mu[e] = 1.0f / (1.0f + __expf(-s));
  }
  float4 m0; m0.x = mu[0]; m0.y = mu[1]; m0.z = mu[2]; m0.w = mu[3];
  float4 m1; m1.x = mu[4]; m1.y = mu[5]; m1.z = mu[6]; m1.w = mu[7];
  *(float4*)(mu_out + (size_t)row * DI + base) = m0;
  *(float4*)(mu_out + (size_t)row * DI + base + 4) = m1;
}

// ---------------------------------------------------------------------------
extern "C" void kernel_launch(void* const* d_in, const int* in_sizes, int n_in,
                              void* d_out, int out_size, void* d_ws, size_t ws_size,
                              hipStream_t stream) {
  (void)in_sizes; (void)n_in; (void)out_size;
  const float* x = (const float*)d_in[0];
  const float* W = (const float*)d_in[1];
  const float* bias = (const float*)d_in[2];
  const float* center = (const float*)d_in[3];
  const float* sharp = (const float*)d_in[4];
  const float* gamma = (const float*)d_in[5];
  const float* beta = (const float*)d_in[6];
  // d_in[7] = top_k (always 256 per setup_inputs)

  float* outY = (float*)d_out;
  float* outMu = outY + (size_t)NB * DO;

  const size_t A_BYTES = (size_t)NB * DI * 2;
  const size_t WB_BYTES = (size_t)DO * DI * 2;
  const size_t PS_BYTES = (size_t)MT * DO * 4;
  const size_t SC_BYTES = (size_t)DO * 4;
  const size_t NEED_BIG = A_BYTES + WB_BYTES + 2 * PS_BYTES + 2 * SC_BYTES;

  char* p = (char*)d_ws;
  bool bigws = (ws_size >= NEED_BIG);
  ushort* A;
  if (bigws) { A = (ushort*)p; p += A_BYTES; }
  else       { A = (ushort*)outMu; }  // park bf16 A in mu region, recompute mu last
  ushort* Wb = (ushort*)p; p += WB_BYTES;
  float* psum = (float*)p; p += PS_BYTES;
  float* psumsq = (float*)p; p += PS_BYTES;
  float* scaleA = (float*)p; p += SC_BYTES;
  float* shiftA = (float*)p;

  k_cvt<<<dim3((DO * DI) / (256 * 8)), dim3(256), 0, stream>>>(W, Wb);
  k_topk<<<dim3(NB), dim3(256), 0, stream>>>(x, center, sharp,
                                             bigws ? outMu : (float*)nullptr, A);
  k_gemm<<<dim3((NB / 256) * (DO / 256)), dim3(512), 0, stream>>>(A, Wb, bias, outY,
                                                                  psum, psumsq);
  k_bnfin<<<dim3(DO / 256), dim3(256), 0, stream>>>(psum, psumsq, gamma, beta,
                                                    scaleA, shiftA);
  k_bnapply<<<dim3((size_t)NB * DO / 4 / 256), dim3(256), 0, stream>>>(outY, scaleA,
                                                                       shiftA);
  if (!bigws) k_mu<<<dim3(NB), dim3(256), 0, stream>>>(x, center, sharp, outMu);
}

// Round 6
// 374.506 us; speedup vs baseline: 1.0267x; 1.0267x over previous
//
#include <hip/hip_runtime.h>
#include <stdint.h>

#define NB 16384       // batch rows
#define DI 2048        // d_in
#define DO 2048        // d_out
#define KTOP 256
#define LIST_CAP 384
#define MT (NB / 256)  // 256-row tiles for partial sums (64)

typedef __attribute__((ext_vector_type(4))) float f32x4;
typedef __attribute__((ext_vector_type(8))) short s16x8;
typedef __attribute__((ext_vector_type(8))) unsigned short u16x8;

// OWA weights: w(rank) = (1 - 0.9*rank/255)/140.8
#define OWA_C0 7.10227273e-3f
#define OWA_C1 2.50668449e-5f

__device__ __forceinline__ ushort f2bf(float f) {
  uint32_t u = __float_as_uint(f);
  uint32_t r = (u + 0x7FFFu + ((u >> 16) & 1u)) >> 16;  // RNE
  return (ushort)r;
}

__device__ __forceinline__ void gld_lds16(const void* g, void* l) {
  __builtin_amdgcn_global_load_lds((__attribute__((address_space(1))) void*)g,
                                   (__attribute__((address_space(3))) void*)l,
                                   16, 0, 0);
}

// ---------------------------------------------------------------------------
// K0: convert W (fp32 [DO][DI]) -> bf16
__global__ __launch_bounds__(256) void k_cvt(const float* __restrict__ W,
                                             ushort* __restrict__ Wb) {
  size_t i = ((size_t)blockIdx.x * 256 + threadIdx.x) * 8;
  float4 a = *(const float4*)(W + i);
  float4 b = *(const float4*)(W + i + 4);
  u16x8 o;
  o[0] = f2bf(a.x); o[1] = f2bf(a.y); o[2] = f2bf(a.z); o[3] = f2bf(a.w);
  o[4] = f2bf(b.x); o[5] = f2bf(b.y); o[6] = f2bf(b.z); o[7] = f2bf(b.w);
  *(u16x8*)(Wb + i) = o;
}

// ---------------------------------------------------------------------------
// K1: per-row mu + top-k(256) OWA -> A (bf16). One block (256 thr) per row.
__global__ __launch_bounds__(256) void k_topk(
    const float* __restrict__ x, const float* __restrict__ center,
    const float* __restrict__ sharp, float* __restrict__ mu_out,
    ushort* __restrict__ A) {
  __shared__ __align__(16) float w_lds[DI];   // OWA weight per column (0 if not selected)
  __shared__ uint32_t histR[8 * 256];         // 8-way replicated histogram
  __shared__ uint64_t list[LIST_CAP];         // candidate keys (bits<<32 | (DI-1-idx))
  __shared__ uint32_t scal[4];

  const int t = threadIdx.x;
  const int lane = t & 63;
  const int wv = t >> 6;
  const int row = blockIdx.x;
  const int base = t * 8;

  const float* xr = x + (size_t)row * DI + base;
  float4 xa = *(const float4*)(xr);
  float4 xb = *(const float4*)(xr + 4);
  float4 ca = *(const float4*)(center + base);
  float4 cb = *(const float4*)(center + base + 4);
  float4 sa = *(const float4*)(sharp + base);
  float4 sb = *(const float4*)(sharp + base + 4);

  float xv[8] = {xa.x, xa.y, xa.z, xa.w, xb.x, xb.y, xb.z, xb.w};
  float cv[8] = {ca.x, ca.y, ca.z, ca.w, cb.x, cb.y, cb.z, cb.w};
  float sv[8] = {sa.x, sa.y, sa.z, sa.w, sb.x, sb.y, sb.z, sb.w};
  float muv[8];
  uint32_t bits[8];
#pragma unroll
  for (int e = 0; e < 8; ++e) {
    float s = sv[e] * (xv[e] - cv[e]);
    float m = 1.0f / (1.0f + __expf(-s));
    muv[e] = m;
    bits[e] = __float_as_uint(m);  // mu>0 -> bit pattern is order-preserving
  }
  if (mu_out) {
    float4 m0; m0.x = muv[0]; m0.y = muv[1]; m0.z = muv[2]; m0.w = muv[3];
    float4 m1; m1.x = muv[4]; m1.y = muv[5]; m1.z = muv[6]; m1.w = muv[7];
    *(float4*)(mu_out + (size_t)row * DI + base) = m0;
    *(float4*)(mu_out + (size_t)row * DI + base + 4) = m1;
  }
  // zero weight array (scattered into much later; barriers in between)
  float4 z4; z4.x = z4.y = z4.z = z4.w = 0.f;
  *(float4*)(w_lds + base) = z4;
  *(float4*)(w_lds + base + 4) = z4;

  // ---- 4-pass byte radix select for the 256th-largest bit pattern ----
  uint32_t maskHi = 0, pfx = 0;
  uint32_t k_rem = KTOP;
  const uint32_t rep = (uint32_t)(t & 7) * 256u;
#pragma unroll 1
  for (int pass = 0; pass < 4; ++pass) {
    const int shift = 24 - pass * 8;
#pragma unroll
    for (int i = 0; i < 8; ++i) histR[t + 256 * i] = 0;
    __syncthreads();
#pragma unroll
    for (int e = 0; e < 8; ++e) {
      uint32_t bb = bits[e];
      if ((bb & maskHi) == pfx)
        atomicAdd(&histR[rep + ((bb >> shift) & 255u)], 1u);
    }
    __syncthreads();
    if (wv == 0) {  // single-wave suffix scan over 256 bins, no barriers
      uint32_t c0 = 0, c1 = 0, c2 = 0, c3 = 0;
#pragma unroll
      for (int r = 0; r < 8; ++r) {
        const uint32_t* h = &histR[r * 256 + lane * 4];
        c0 += h[0]; c1 += h[1]; c2 += h[2]; c3 += h[3];
      }
      uint32_t s3 = c3, s2 = c2 + s3, s1 = c1 + s2, s0 = c0 + s1;
      uint32_t Tl = s0, suf = s0;
#pragma unroll
      for (int off = 1; off < 64; off <<= 1) {
        uint32_t vsh = __shfl_down(suf, off);
        if (lane + off < 64) suf += vsh;
      }
      uint32_t above = suf - Tl;  // total of lanes > lane
      uint32_t SS[4] = {s0 + above, s1 + above, s2 + above, s3 + above};
      uint32_t cc[4] = {c0, c1, c2, c3};
#pragma unroll
      for (int j = 0; j < 4; ++j) {
        if (SS[j] >= k_rem && (SS[j] - cc[j]) < k_rem) {
          scal[0] = (uint32_t)(lane * 4 + j);
          scal[1] = SS[j] - cc[j];  // count strictly greater (this level)
        }
      }
    }
    __syncthreads();
    uint32_t v = scal[0], g = scal[1];
    pfx |= (v << shift);
    maskHi |= (0xFFu << shift);
    k_rem -= g;
  }
  const uint32_t tb = pfx;  // exact bit pattern of the 256th largest

  // ---- compact candidates (bits >= tb) ----
  if (t == 0) scal[2] = 0;
  __syncthreads();
#pragma unroll
  for (int e = 0; e < 8; ++e) {
    if (bits[e] >= tb) {
      uint32_t pos = atomicAdd(&scal[2], 1u);
      if (pos < LIST_CAP)
        list[pos] = ((uint64_t)bits[e] << 32) |
                    (uint64_t)(uint32_t)(DI - 1 - (base + e));
    }
  }
  __syncthreads();
  int L = (int)scal[2];
  if (L > LIST_CAP) L = LIST_CAP;

  // ---- exact ranks among candidates (key includes stable index tiebreak) ----
  for (int sIdx = t; sIdx < L; sIdx += 256) {
    uint64_t key = list[sIdx];
    int rank = 0;
#pragma unroll 4
    for (int j = 0; j < L; ++j) rank += (int)(list[j] > key);
    if (rank < KTOP) {
      int idx = DI - 1 - (int)((uint32_t)key & 0xFFFFFFFFu);
      w_lds[idx] = OWA_C0 - OWA_C1 * (float)rank;
    }
  }
  __syncthreads();

  // ---- emit A[b,i] = w * mu * x as bf16 (coalesced 16B stores) ----
  u16x8 ov;
#pragma unroll
  for (int e = 0; e < 8; ++e) ov[e] = f2bf(w_lds[base + e] * muv[e] * xv[e]);
  *(u16x8*)(A + (size_t)row * DI + base) = ov;
}

// ---------------------------------------------------------------------------
// K2: 256x256x64 8-phase GEMM, R6: REGISTER-PIPELINED fragments.
//
// Phase q's top issues ds_reads for phase q+1 into the alternate reg buffer
// (bufA_/bufB_ ping-pong, all-static indices); the pre-MFMA wait is
// lgkmcnt(4) on reads issued a FULL PHASE earlier (~free). B(T+1) fragments
// are read at (T,3) AFTER its MFMA consumed breg (no WAR, no double-buffer);
// legal because B(T+1) is vmcnt-forced at (T,2) and published by its barrier.
//
// Stages: (T,0):A(T+1)h0  (T,1):A(T+1)h1  (T,2):B(T+2)h0  (T,3):B(T+2)h1
// vmcnt:  (T,0) tail vmcnt(6) -> forces A(T)h1   (read at (T,1) top)
//         (T,2) tail vmcnt(4) -> forces B(T+1)+A(T+1)h0 (read at (T,3))
//         T==30: vmcnt(2); tile 31 peeled, (31,0) tail vmcnt(0).
// Steady in-flight: 6 entering each tile; max 10. Never vmcnt(0) in loop.
// Chunk-XOR swizzle (R2, 0-conflict): LDS[row][c] = global[row][c ^ (row&7)].
#define HALFS 8192  // ushorts per half-slot (128 rows x 64 cols)

#define MFMA(a, b, c) __builtin_amdgcn_mfma_f32_16x16x32_bf16(a, b, c, 0, 0, 0)

#define STAGE_A(U, h)                                                       \
  do {                                                                      \
    ushort* sl = lA + (((((U) & 1) << 1) + (h)) * HALFS);                   \
    gld_lds16(pA0 + (size_t)((h) * 128) * DI + (size_t)(U) * 64, sl + d0);  \
    gld_lds16(pA0 + (size_t)((h) * 128 + 64) * DI + (size_t)(U) * 64,       \
              sl + d1);                                                     \
  } while (0)

#define STAGE_B(U, h)                                                       \
  do {                                                                      \
    ushort* sl = lB + (((((U) & 1) << 1) + (h)) * HALFS);                   \
    gld_lds16(pB0 + (size_t)((h) * 128) * DI + (size_t)(U) * 64, sl + d0);  \
    gld_lds16(pB0 + (size_t)((h) * 128 + 64) * DI + (size_t)(U) * 64,       \
              sl + d1);                                                     \
  } while (0)

// read 4 A-fragments (one phase's worth) into BUF (static indices)
#define RD_A(BUF, slotp, rowb)                                              \
  do {                                                                      \
    const ushort* rp_ = (slotp) + ((rowb) + fr) * 64;                       \
    BUF[0] = *(const s16x8*)(rp_ + c0);                                     \
    BUF[1] = *(const s16x8*)(rp_ + c1);                                     \
    BUF[2] = *(const s16x8*)(rp_ + 16 * 64 + c0);                           \
    BUF[3] = *(const s16x8*)(rp_ + 16 * 64 + c1);                           \
  } while (0)

#define RD_B(slotp)                                                         \
  do {                                                                      \
    _Pragma("unroll") for (int ni = 0; ni < 4; ++ni) {                      \
      breg[ni][0] = *(const s16x8*)((slotp) + ni * 1024 + boff + c0);       \
      breg[ni][1] = *(const s16x8*)((slotp) + ni * 1024 + boff + c1);       \
    }                                                                       \
  } while (0)

#define MFMA_PHASE(q, BUF)                                                  \
  do {                                                                      \
    __builtin_amdgcn_s_setprio(1);                                          \
    _Pragma("unroll") for (int ni = 0; ni < 4; ++ni) {                      \
      acc[2 * (q)][ni] = MFMA(BUF[0], breg[ni][0], acc[2 * (q)][ni]);       \
      acc[2 * (q)][ni] = MFMA(BUF[1], breg[ni][1], acc[2 * (q)][ni]);       \
      acc[2 * (q) + 1][ni] = MFMA(BUF[2], breg[ni][0], acc[2 * (q) + 1][ni]); \
      acc[2 * (q) + 1][ni] = MFMA(BUF[3], breg[ni][1], acc[2 * (q) + 1][ni]); \
    }                                                                       \
    __builtin_amdgcn_s_setprio(0);                                          \
  } while (0)

#define PHASE(q, RD_STMT, STAGE_STMT, BUF, POST_STMT, TAIL_STMT, LG)        \
  do {                                                                      \
    RD_STMT;                                                                \
    STAGE_STMT;                                                             \
    __builtin_amdgcn_s_barrier();                                           \
    asm volatile("s_waitcnt lgkmcnt(" LG ")" ::: "memory");                 \
    __builtin_amdgcn_sched_barrier(0);                                      \
    MFMA_PHASE(q, BUF);                                                     \
    POST_STMT;                                                              \
    TAIL_STMT;                                                              \
    __builtin_amdgcn_s_barrier();                                           \
  } while (0)

__global__ __launch_bounds__(512, 2) void k_gemm(
    const ushort* __restrict__ A, const ushort* __restrict__ Wb,
    const float* __restrict__ bias, float* __restrict__ outp,
    float* __restrict__ psum, float* __restrict__ psumsq) {
  __shared__ __align__(16) ushort lA[4 * HALFS];
  __shared__ __align__(16) ushort lB[4 * HALFS];

  const int t = threadIdx.x;
  const int lane = t & 63;
  const int wv = t >> 6;
  const int wm = wv >> 2;   // 0..1: row-group parity (rows 64q + wm*32 + [0,32))
  const int wn = wv & 3;    // 0..3: 64-col strip of the N tile
  const int wm32 = wm * 32;
  const int fr = lane & 15;
  const int kg = lane >> 4;
  const int s = fr & 7;

  // XCD-aware bijective swizzle (512 blocks, 512 % 8 == 0)
  int bid = blockIdx.x;
  int orig = (bid & 7) * 64 + (bid >> 3);
  const int nb = orig & 7;
  const int mb = orig >> 3;
  const int m0 = mb * 256;
  const int n0 = nb * 256;

  // staging: thread t covers in-slot rows t>>3 (load0), 64+(t>>3) (load1);
  // chunk t&7 holds global chunk (t&7)^(row&7)
  const int srow0 = t >> 3;
  const int scol = ((t & 7) ^ (srow0 & 7)) * 8;
  const ushort* pA0 = A + (size_t)(m0 + srow0) * DI + scol;
  const ushort* pB0 = Wb + (size_t)(n0 + srow0) * DI + scol;
  const int d0 = t * 8;          // LDS dst (ushorts) for load 0
  const int d1 = (512 + t) * 8;  // load 1

  f32x4 acc[8][4];
#pragma unroll
  for (int i = 0; i < 8; ++i)
#pragma unroll
    for (int j = 0; j < 4; ++j) acc[i][j] = (f32x4){0.f, 0.f, 0.f, 0.f};

  // fragment read offsets (ushorts)
  const int c0 = (kg ^ s) * 8;
  const int c1 = ((4 + kg) ^ s) * 8;
  const int boff = ((wn & 1) * 64 + fr) * 64;

  s16x8 breg[4][2];
  s16x8 bufA_[4], bufB_[4];  // ping-pong A fragments (phases 0,2 / 1,3)

  // prologue: B(0), A(0), B(1) = 12 loads; vmcnt(6) forces B(0)+A(0)h0
  STAGE_B(0, 0); STAGE_B(0, 1);
  STAGE_A(0, 0); STAGE_A(0, 1);
  STAGE_B(1, 0); STAGE_B(1, 1);
  asm volatile("s_waitcnt vmcnt(6)" ::: "memory");
  __builtin_amdgcn_s_barrier();
  RD_B(lB + (wn >> 1) * HALFS);       // B(0) frags (parity-0 slots)
  RD_A(bufA_, lA, wm32);              // phase-0 frags (parity-0 h0)

#pragma unroll 1
  for (int T = 0; T < 31; ++T) {
    const ushort* lAcur = lA + ((T & 1) << 1) * HALFS;
    const ushort* lAnxt = lA + (((T + 1) & 1) << 1) * HALFS;
    const ushort* sBnxt = lB + ((((T + 1) & 1) << 1) + (wn >> 1)) * HALFS;

    PHASE(0, RD_A(bufB_, lAcur, 64 + wm32), STAGE_A(T + 1, 0), bufA_, ,
          asm volatile("s_waitcnt vmcnt(6)" ::: "memory"), "4");
    PHASE(1, RD_A(bufA_, lAcur + HALFS, wm32), STAGE_A(T + 1, 1), bufB_, , ,
          "4");
    PHASE(2, RD_A(bufB_, lAcur + HALFS, 64 + wm32),
          if (T < 30) STAGE_B(T + 2, 0), bufA_, ,
          if (T < 30) { asm volatile("s_waitcnt vmcnt(4)" ::: "memory"); }
          else { asm volatile("s_waitcnt vmcnt(2)" ::: "memory"); }, "4");
    PHASE(3, RD_A(bufA_, lAnxt, wm32), if (T < 30) STAGE_B(T + 2, 1), bufB_,
          RD_B(sBnxt), , "4");
  }
  {  // tile 31 (peeled: no stages, no next-tile reads)
    const ushort* lAcur = lA + 2 * HALFS;  // parity 1
    PHASE(0, RD_A(bufB_, lAcur, 64 + wm32), , bufA_, ,
          asm volatile("s_waitcnt vmcnt(0)" ::: "memory"), "4");
    PHASE(1, RD_A(bufA_, lAcur + HALFS, wm32), , bufB_, , , "4");
    PHASE(2, RD_A(bufB_, lAcur + HALFS, 64 + wm32), , bufA_, , , "4");
    PHASE(3, , , bufB_, , , "0");
  }

  // epilogue: bias + relu + store + deterministic column partials
  __syncthreads();
  float* colsum = (float*)lA;     // reuse tile LDS
  float* colsq = colsum + 256;
  if (t < 256) { colsum[t] = 0.f; colsq[t] = 0.f; }
  __syncthreads();
#pragma unroll
  for (int ni = 0; ni < 4; ++ni) {
    const int n = n0 + wn * 64 + ni * 16 + fr;
    const float bv = bias[n];
    float cs = 0.f, cq = 0.f;
#pragma unroll
    for (int mi = 0; mi < 8; ++mi) {
      // acc[mi] -> tile row 64*(mi>>1) + wm*32 + 16*(mi&1) + kg*4 + r
      const int rowb = m0 + 64 * (mi >> 1) + wm32 + 16 * (mi & 1) + kg * 4;
      f32x4 v = acc[mi][ni];
#pragma unroll
      for (int r = 0; r < 4; ++r) {
        float zz = fmaxf(v[r] + bv, 0.f);
        outp[(size_t)(rowb + r) * DO + n] = zz;
        cs += zz;
        cq += zz * zz;
      }
    }
    cs += __shfl_xor(cs, 16); cq += __shfl_xor(cq, 16);
    cs += __shfl_xor(cs, 32); cq += __shfl_xor(cq, 32);
    if (kg == 0) {  // exactly 2 waves (wm=0,1) add per column bin
      atomicAdd(&colsum[wn * 64 + ni * 16 + fr], cs);
      atomicAdd(&colsq[wn * 64 + ni * 16 + fr], cq);
    }
  }
  __syncthreads();
  if (t < 256) {
    psum[(size_t)mb * DO + n0 + t] = colsum[t];
    psumsq[(size_t)mb * DO + n0 + t] = colsq[t];
  }
}

// ---------------------------------------------------------------------------
// K3: finalize BN scale/shift per column
__global__ __launch_bounds__(256) void k_bnfin(
    const float* __restrict__ psum, const float* __restrict__ psumsq,
    const float* __restrict__ gamma, const float* __restrict__ beta,
    float* __restrict__ scaleA, float* __restrict__ shiftA) {
  int n = blockIdx.x * 256 + threadIdx.x;
  float s = 0.f, q = 0.f;
  for (int r = 0; r < MT; ++r) {
    s += psum[(size_t)r * DO + n];
    q += psumsq[(size_t)r * DO + n];
  }
  float mean = s * (1.0f / (float)NB);
  float var = q * (1.0f / (float)NB) - mean * mean;
  var = fmaxf(var, 0.f);
  float rstd = rsqrtf(var + 1e-5f);
  float sc = gamma[n] * rstd;
  scaleA[n] = sc;
  shiftA[n] = beta[n] - mean * sc;
}

// ---------------------------------------------------------------------------
// K4: y = out*scale + shift, in place over the y region
__global__ __launch_bounds__(256) void k_bnapply(float* __restrict__ outp,
                                                 const float* __restrict__ scaleA,
                                                 const float* __restrict__ shiftA) {
  size_t i = ((size_t)blockIdx.x * 256 + threadIdx.x) * 4;
  int n = (int)(i & (DO - 1));
  float4 v = *(float4*)(outp + i);
  float4 sc = *(const float4*)(scaleA + n);
  float4 sh = *(const float4*)(shiftA + n);
  v.x = v.x * sc.x + sh.x;
  v.y = v.y * sc.y + sh.y;
  v.z = v.z * sc.z + sh.z;
  v.w = v.w * sc.w + sh.w;
  *(float4*)(outp + i) = v;
}

// ---------------------------------------------------------------------------
// K5 (small-ws fallback): recompute mu into the mu region
__global__ __launch_bounds__(256) void k_mu(const float* __restrict__ x,
                                            const float* __restrict__ center,
                                            const float* __restrict__ sharp,
                                            float* __restrict__ mu_out) {
  const int t = threadIdx.x;
  const int row = blockIdx.x;
  const int base = t * 8;
  const float* xr = x + (size_t)row * DI + base;
  float4 xa = *(const float4*)(xr);
  float4 xb = *(const float4*)(xr + 4);
  float4 ca = *(const float4*)(center + base);
  float4 cb = *(const float4*)(center + base + 4);
  float4 sa = *(const float4*)(sharp + base);
  float4 sb = *(const float4*)(sharp + base + 4);
  float xv[8] = {xa.x, xa.y, xa.z, xa.w, xb.x, xb.y, xb.z, xb.w};
  float cv[8] = {ca.x, ca.y, ca.z, ca.w, cb.x, cb.y, cb.z, cb.w};
  float sv[8] = {sa.x, sa.y, sa.z, sa.w, sb.x, sb.y, sb.z, sb.w};
  float mu[8];
#pragma unroll
  for (int e = 0; e < 8; ++e) {
    float s = sv[e] * (xv[e] - cv[e]);
    mu[e] = 1.0f / (1.0f + __expf(-s));
  }
  float4 m0; m0.x = mu[0]; m0.y = mu[1]; m0.z = mu[2]; m0.w = mu[3];
  float4 m1; m1.x = mu[4]; m1.y = mu[5]; m1.z = mu[6]; m1.w = mu[7];
  *(float4*)(mu_out + (size_t)row * DI + base) = m0;
  *(float4*)(mu_out + (size_t)row * DI + base + 4) = m1;
}

// ---------------------------------------------------------------------------
extern "C" void kernel_launch(void* const* d_in, const int* in_sizes, int n_in,
                              void* d_out, int out_size, void* d_ws, size_t ws_size,
                              hipStream_t stream) {
  (void)in_sizes; (void)n_in; (void)out_size;
  const float* x = (const float*)d_in[0];
  const float* W = (const float*)d_in[1];
  const float* bias = (const float*)d_in[2];
  const float* center = (const float*)d_in[3];
  const float* sharp = (const float*)d_in[4];
  const float* gamma = (const float*)d_in[5];
  const float* beta = (const float*)d_in[6];
  // d_in[7] = top_k (always 256 per setup_inputs)

  float* outY = (float*)d_out;
  float* outMu = outY + (size_t)NB * DO;

  const size_t A_BYTES = (size_t)NB * DI * 2;
  const size_t WB_BYTES = (size_t)DO * DI * 2;
  const size_t PS_BYTES = (size_t)MT * DO * 4;
  const size_t SC_BYTES = (size_t)DO * 4;
  const size_t NEED_BIG = A_BYTES + WB_BYTES + 2 * PS_BYTES + 2 * SC_BYTES;

  char* p = (char*)d_ws;
  bool bigws = (ws_size >= NEED_BIG);
  ushort* A;
  if (bigws) { A = (ushort*)p; p += A_BYTES; }
  else       { A = (ushort*)outMu; }  // park bf16 A in mu region, recompute mu last
  ushort* Wb = (ushort*)p; p += WB_BYTES;
  float* psum = (float*)p; p += PS_BYTES;
  float* psumsq = (float*)p; p += PS_BYTES;
  float* scaleA = (float*)p; p += SC_BYTES;
  float* shiftA = (float*)p;

  k_cvt<<<dim3((DO * DI) / (256 * 8)), dim3(256), 0, stream>>>(W, Wb);
  k_topk<<<dim3(NB), dim3(256), 0, stream>>>(x, center, sharp,
                                             bigws ? outMu : (float*)nullptr, A);
  k_gemm<<<dim3((NB / 256) * (DO / 256)), dim3(512), 0, stream>>>(A, Wb, bias, outY,
                                                                  psum, psumsq);
  k_bnfin<<<dim3(DO / 256), dim3(256), 0, stream>>>(psum, psumsq, gamma, beta,
                                                    scaleA, shiftA);
  k_bnapply<<<dim3((size_t)NB * DO / 4 / 256), dim3(256), 0, stream>>>(outY, scaleA,
                                                                       shiftA);
  if (!bigws) k_mu<<<dim3(NB), dim3(256), 0, stream>>>(x, center, sharp, outMu);
}